// Round 6
// baseline (652.985 us; speedup 1.0000x reference)
//
#include <hip/hip_runtime.h>
#include <hip/hip_bf16.h>

// PQLinear: C[8192,4096] = X[8192,4096] @ W[4096,4096]^T
//   W[o][k] = codebooks[k/128][assignments[o][k/128]][k%128]
// R6: kill the convert_x pass. GEMM reads X fp32 directly; A-tiles are
// reg-staged (load f32 -> cvt bf16 -> ds_write), B (gathered W) keeps the
// R5 gload_lds counted-vmcnt pipeline. A: 2 LDS slots, B: 4 slots, 96 KiB.
// ws usage: Wb only = 33.5 MB.

#define K_DIM 4096
#define N_DIM 4096
#define M_DIM 8192

typedef __attribute__((ext_vector_type(8))) __bf16 bf16x8;
typedef __attribute__((ext_vector_type(4))) float f32x4;
typedef __attribute__((ext_vector_type(8))) unsigned short ushort8;

__device__ __forceinline__ unsigned short f2bf_rne(float f) {
    unsigned u = __builtin_bit_cast(unsigned, f);
    u += 0x7fffu + ((u >> 16) & 1u);   // RNE (inputs are finite randn)
    return (unsigned short)(u >> 16);
}

// ---------------------------------------------------------------------------
// Kernel 1: gather + convert W -> bf16. grid-stride, 2048 blocks. (unchanged)
__global__ void gather_w_kernel(const float* __restrict__ cb,
                                const int* __restrict__ asn,
                                unsigned short* __restrict__ Wb) {
    for (int gid = blockIdx.x * 256 + threadIdx.x; gid < (N_DIM << 9);
         gid += 2048 * 256) {
        int o = gid >> 9;
        int k = (gid & 511) << 3;
        int s = k >> 7;
        int c = asn[(o << 5) + s];
        const float* src = cb + ((((s << 8) + c) << 7) + (k & 127));
        float4 v0 = *(const float4*)src;
        float4 v1 = *(const float4*)(src + 4);
        ushort8 r;
        r[0] = f2bf_rne(v0.x); r[1] = f2bf_rne(v0.y);
        r[2] = f2bf_rne(v0.z); r[3] = f2bf_rne(v0.w);
        r[4] = f2bf_rne(v1.x); r[5] = f2bf_rne(v1.y);
        r[6] = f2bf_rne(v1.z); r[7] = f2bf_rne(v1.w);
        *(ushort8*)(Wb + (size_t)o * K_DIM + k) = r;
    }
}

// ---------------------------------------------------------------------------
// Kernel 2: fused-convert pipelined GEMM. C = X * W^T.
// 512 thr = 8 waves (2Mx4N); wave owns 128x64 of the 256x256 tile. BK=32.
// LDS: A 2 slots x 16 KiB (bf16, written via ds_write) + B 4 slots x 16 KiB
// (bf16, written via gload_lds DMA) = 96 KiB. Swizzle: phys 16B-slot =
// logical ^ ((row>>1)&3), applied on A-write/A-read and B-source/B-read.
#define T_TILES 128          // K/BK
#define ASLOT_E 8192         // 256 rows x 32 elems
#define BBASE_E 16384        // after A's 2 slots
#define FENCE asm volatile("" ::: "memory")

__global__ __launch_bounds__(512, 2) void gemm_fused_kernel(
    const float* __restrict__ X, const __bf16* __restrict__ B,
    float* __restrict__ C) {
    constexpr int K = K_DIM, N = N_DIM;
    extern __shared__ __bf16 lds[];      // 49152 elems = 96 KiB

    const int tid = threadIdx.x;
    const int w   = tid >> 6;
    const int l   = tid & 63;
    const int wr  = w >> 2, wc = w & 3;
    const int lr  = l & 15;
    const int khr = l >> 4;

    const int bid = blockIdx.x;          // 512 = 64/XCD, bijective
    const int swz = (bid & 7) * 64 + (bid >> 3);
    const long m0 = (long)(swz >> 4) * 256;
    const long n0 = (long)(swz & 15) * 256;

    // --- B staging via gload_lds (R5 scheme, pre-swizzled source col) ------
    const int scol = (((l & 3) ^ ((l >> 3) & 3)) << 3);
    const int srow = w * 32 + (l >> 2);
    const __bf16* gB0 = B + (n0 + srow) * (long)K + scol;
    const __bf16* gB1 = gB0 + 16 * (long)K;

    // --- A reg staging: lane handles row w*32+(l>>1), cols (l&1)*16..+16 ---
    const int arow = w * 32 + (l >> 1);
    const float* pX = X + (m0 + arow) * (long)K + ((l & 1) * 16);
    const int p0 = (2 * (l & 1))     ^ ((l >> 2) & 3);   // phys 16B slots
    const int p1 = (2 * (l & 1) + 1) ^ ((l >> 2) & 3);   // ((row>>1)&3 xor)

    // --- fragment read offsets (swizzled, R5-identical pattern) ------------
    const int sw    = (lr >> 1) & 3;
    const int aoff0 = (wr * 128 + lr) * 32 + ((khr ^ sw) << 3);
    const int boff0 = (wc * 64 + lr) * 32 + ((khr ^ sw) << 3);

    f32x4 acc[8][4] = {};
    float4 ar0, ar1, ar2, ar3;           // one in-flight A set (16 VGPR)

    #define A_ISSUE(t) do {                                                   \
        const float* p_ = pX + (long)(t) * 32;                                \
        ar0 = *(const float4*)(p_);      ar1 = *(const float4*)(p_ + 4);      \
        ar2 = *(const float4*)(p_ + 8);  ar3 = *(const float4*)(p_ + 12);     \
    } while (0)

    #define B_ISSUE(t) do {                                                   \
        __bf16* bb_ = lds + BBASE_E + ((t) & 3) * ASLOT_E;                    \
        const long ko_ = (long)(t) * 32;                                      \
        __builtin_amdgcn_global_load_lds(                                     \
            (const __attribute__((address_space(1))) void*)(gB0 + ko_),       \
            (__attribute__((address_space(3))) void*)(bb_ + (w * 32) * 32),   \
            16, 0, 0);                                                        \
        __builtin_amdgcn_global_load_lds(                                     \
            (const __attribute__((address_space(1))) void*)(gB1 + ko_),       \
            (__attribute__((address_space(3))) void*)(bb_ + (w * 32 + 16) * 32),\
            16, 0, 0);                                                        \
    } while (0)

    #define A_WRITE(t) do {                                                   \
        __bf16* d_ = lds + ((t) & 1) * ASLOT_E + arow * 32;                   \
        ushort8 w0, w1;                                                       \
        w0[0] = f2bf_rne(ar0.x); w0[1] = f2bf_rne(ar0.y);                     \
        w0[2] = f2bf_rne(ar0.z); w0[3] = f2bf_rne(ar0.w);                     \
        w0[4] = f2bf_rne(ar1.x); w0[5] = f2bf_rne(ar1.y);                     \
        w0[6] = f2bf_rne(ar1.z); w0[7] = f2bf_rne(ar1.w);                     \
        w1[0] = f2bf_rne(ar2.x); w1[1] = f2bf_rne(ar2.y);                     \
        w1[2] = f2bf_rne(ar2.z); w1[3] = f2bf_rne(ar2.w);                     \
        w1[4] = f2bf_rne(ar3.x); w1[5] = f2bf_rne(ar3.y);                     \
        w1[6] = f2bf_rne(ar3.z); w1[7] = f2bf_rne(ar3.w);                     \
        *(bf16x8*)(d_ + p0 * 8) = __builtin_bit_cast(bf16x8, w0);             \
        *(bf16x8*)(d_ + p1 * 8) = __builtin_bit_cast(bf16x8, w1);             \
    } while (0)

    #define COMPUTE(t) do {                                                   \
        const __bf16* pa_ = lds + ((t) & 1) * ASLOT_E + aoff0;                \
        const __bf16* pb_ = lds + BBASE_E + ((t) & 3) * ASLOT_E + boff0;      \
        bf16x8 bf_[4];                                                        \
        _Pragma("unroll")                                                     \
        for (int n = 0; n < 4; ++n) bf_[n] = *(const bf16x8*)(pb_ + n * 512); \
        __builtin_amdgcn_s_setprio(1);                                        \
        _Pragma("unroll")                                                     \
        for (int m = 0; m < 8; ++m) {                                         \
            bf16x8 af_ = *(const bf16x8*)(pa_ + m * 512);                     \
            _Pragma("unroll")                                                 \
            for (int n = 0; n < 4; ++n)                                       \
                acc[m][n] = __builtin_amdgcn_mfma_f32_16x16x32_bf16(          \
                    af_, bf_[n], acc[m][n], 0, 0, 0);                         \
        }                                                                     \
        __builtin_amdgcn_s_setprio(0);                                        \
    } while (0)

    // ITER: wait B(t) in LDS (counted), drain own ds_writes, barrier, issue
    // next A-regs (t+1) and B-DMA (t+3), compute tile t, then cvt+write
    // A(t+1) (compiler inserts the reg-load wait; B(t+3) after A(t+1) in
    // the queue keeps my counts conservative).
    #define ITER(t, FS, DA, DB, DW) do {                                      \
        asm volatile("s_waitcnt vmcnt(" FS ")" ::: "memory");                 \
        asm volatile("s_waitcnt lgkmcnt(0)" ::: "memory");                    \
        __builtin_amdgcn_s_barrier();                                         \
        FENCE;                                                                \
        if (DA) { A_ISSUE((t) + 1); }                                         \
        FENCE;                                                                \
        if (DB) { B_ISSUE((t) + 3); }                                         \
        FENCE;                                                                \
        COMPUTE(t);                                                           \
        if (DW) { A_WRITE((t) + 1); }                                         \
    } while (0)

    // prologue: A(0) regs; B(0..2) DMA. 6 vm-ops after A(0) -> vmcnt(6).
    A_ISSUE(0); FENCE;
    B_ISSUE(0); FENCE; B_ISSUE(1); FENCE; B_ISSUE(2); FENCE;
    asm volatile("s_waitcnt vmcnt(6)" ::: "memory");
    A_WRITE(0);                          // -> A slot 0

    // F values = #vm-ops issued after B(t) at the wait point (fenced order):
    // t=0: B(1)+B(2)=4; t=1: B(2)+iter0's 6=8; t>=2 steady: 12;
    // tail: t=125: 12; t=126: 10; t=127: 8.
    ITER(0, "4", 1, 1, 1);
    ITER(1, "8", 1, 1, 1);
    for (int t = 2; t <= 124; ++t) ITER(t, "12", 1, 1, 1);
    ITER(125, "12", 1, 0, 1);
    ITER(126, "10", 1, 0, 1);
    ITER(127, "8",  0, 0, 0);

    // C/D layout (m89-verified): col = lane&15, row = (lane>>4)*4 + reg
    const int crow = khr * 4;
    #pragma unroll
    for (int m = 0; m < 8; ++m)
        #pragma unroll
        for (int n = 0; n < 4; ++n) {
            float* cp = C + (m0 + wr * 128 + m * 16 + crow) * (long)N
                          + n0 + wc * 64 + n * 16 + lr;
            #pragma unroll
            for (int j = 0; j < 4; ++j) cp[(long)j * N] = acc[m][n][j];
        }
    #undef A_ISSUE
    #undef B_ISSUE
    #undef A_WRITE
    #undef COMPUTE
    #undef ITER
}

// ---------------------------------------------------------------------------
extern "C" void kernel_launch(void* const* d_in, const int* in_sizes, int n_in,
                              void* d_out, int out_size, void* d_ws, size_t ws_size,
                              hipStream_t stream) {
    const float* x   = (const float*)d_in[0];   // [4,2048,4096] fp32
    const float* cb  = (const float*)d_in[1];   // [32,256,128] fp32
    const int*   asn = (const int*)d_in[2];     // [4096,32] int32
    float* out = (float*)d_out;                 // [4,2048,4096] fp32

    unsigned short* Wb = (unsigned short*)d_ws; // 33.5 MB

    gather_w_kernel<<<2048, 256, 0, stream>>>(cb, asn, Wb);
    // 512 blocks = 32 m-tiles x 16 n-tiles; 96 KiB dynamic LDS
    gemm_fused_kernel<<<512, 512, 98304, stream>>>(
        x, (const __bf16*)Wb, out);
}

// Round 9
// 606.476 us; speedup vs baseline: 1.0767x; 1.0767x over previous
//
#include <hip/hip_runtime.h>
#include <hip/hip_bf16.h>

// PQLinear: C[8192,4096] = X[8192,4096] @ W[4096,4096]^T
//   W[o][k] = codebooks[k/128][assignments[o][k/128]][k%128]
// R9: R8 schedule, compile-fixed for real this time: A register sets are a
// plain struct (two NAMED instances sA/sB, static member access — rule #20),
// macros take the set as ONE identifier argument (no token pasting, no
// arg-count games). Schedule: depth-2 A reg pipeline (iter t loads A(t+2)
// into one set, cvt+ds_writes A(t+1) from the other, loaded a full iter
// earlier); B keeps the R5 counted-vmcnt 4-slot gload_lds pipeline (never
// drained in-loop); head-race-fixed prologue order A0,B0,A1,B1,B2.
// LDS 96 KiB: A 2x16KiB (ds_write) + B 4x16KiB (gload_lds DMA).

#define K_DIM 4096
#define N_DIM 4096
#define M_DIM 8192

typedef __attribute__((ext_vector_type(8))) __bf16 bf16x8;
typedef __attribute__((ext_vector_type(4))) float f32x4;
typedef __attribute__((ext_vector_type(8))) unsigned short ushort8;

__device__ __forceinline__ unsigned short f2bf_rne(float f) {
    unsigned u = __builtin_bit_cast(unsigned, f);
    u += 0x7fffu + ((u >> 16) & 1u);   // RNE (inputs are finite randn)
    return (unsigned short)(u >> 16);
}

// ---------------------------------------------------------------------------
// Kernel 1: gather + convert W -> bf16. grid-stride, 2048 blocks. (unchanged)
__global__ void gather_w_kernel(const float* __restrict__ cb,
                                const int* __restrict__ asn,
                                unsigned short* __restrict__ Wb) {
    for (int gid = blockIdx.x * 256 + threadIdx.x; gid < (N_DIM << 9);
         gid += 2048 * 256) {
        int o = gid >> 9;
        int k = (gid & 511) << 3;
        int s = k >> 7;
        int c = asn[(o << 5) + s];
        const float* src = cb + ((((s << 8) + c) << 7) + (k & 127));
        float4 v0 = *(const float4*)src;
        float4 v1 = *(const float4*)(src + 4);
        ushort8 r;
        r[0] = f2bf_rne(v0.x); r[1] = f2bf_rne(v0.y);
        r[2] = f2bf_rne(v0.z); r[3] = f2bf_rne(v0.w);
        r[4] = f2bf_rne(v1.x); r[5] = f2bf_rne(v1.y);
        r[6] = f2bf_rne(v1.z); r[7] = f2bf_rne(v1.w);
        *(ushort8*)(Wb + (size_t)o * K_DIM + k) = r;
    }
}

// ---------------------------------------------------------------------------
// Kernel 2: fused-convert pipelined GEMM. C = X * W^T.
// 512 thr = 8 waves (2Mx4N); wave owns 128x64 of the 256x256 tile. BK=32.
// Swizzle (both sides): phys 16B-slot = logical ^ ((row>>1)&3).
#define T_TILES 128          // K/BK
#define ASLOT_E 8192         // 256 rows x 32 elems
#define BBASE_E 16384        // after A's 2 slots
#define FENCE asm volatile("" ::: "memory")

struct ASet { float4 r0, r1, r2, r3; };   // one in-flight A tile (16 VGPR)

__global__ __launch_bounds__(512, 2) void gemm_fused_kernel(
    const float* __restrict__ X, const __bf16* __restrict__ B,
    float* __restrict__ C) {
    constexpr int K = K_DIM, N = N_DIM;
    extern __shared__ __bf16 lds[];      // 49152 elems = 96 KiB

    const int tid = threadIdx.x;
    const int w   = tid >> 6;
    const int l   = tid & 63;
    const int wr  = w >> 2, wc = w & 3;
    const int lr  = l & 15;
    const int khr = l >> 4;

    const int bid = blockIdx.x;          // 512 = 64/XCD, bijective
    const int swz = (bid & 7) * 64 + (bid >> 3);
    const long m0 = (long)(swz >> 4) * 256;
    const long n0 = (long)(swz & 15) * 256;

    // --- B staging via gload_lds (R5 scheme, pre-swizzled source col) ------
    const int scol = (((l & 3) ^ ((l >> 3) & 3)) << 3);
    const int srow = w * 32 + (l >> 2);
    const __bf16* gB0 = B + (n0 + srow) * (long)K + scol;
    const __bf16* gB1 = gB0 + 16 * (long)K;

    // --- A reg staging: lane covers row w*32+(l>>1), cols (l&1)*16..+16 ---
    const int arow = w * 32 + (l >> 1);
    const float* pX = X + (m0 + arow) * (long)K + ((l & 1) * 16);
    const int p0 = (2 * (l & 1))     ^ ((l >> 2) & 3);   // phys 16B slots
    const int p1 = (2 * (l & 1) + 1) ^ ((l >> 2) & 3);

    // --- fragment read offsets (swizzled) ----------------------------------
    const int sw    = (lr >> 1) & 3;
    const int aoff0 = (wr * 128 + lr) * 32 + ((khr ^ sw) << 3);
    const int boff0 = (wc * 64 + lr) * 32 + ((khr ^ sw) << 3);

    f32x4 acc[8][4] = {};
    ASet sA, sB;                         // two NAMED sets, static access only

    #define A_ISSUE(t, S) do {                                                \
        const float* p_ = pX + (long)(t) * 32;                                \
        S.r0 = *(const float4*)(p_);      S.r1 = *(const float4*)(p_ + 4);    \
        S.r2 = *(const float4*)(p_ + 8);  S.r3 = *(const float4*)(p_ + 12);   \
    } while (0)

    #define B_ISSUE(t) do {                                                   \
        __bf16* bb_ = lds + BBASE_E + ((t) & 3) * ASLOT_E;                    \
        const long ko_ = (long)(t) * 32;                                      \
        __builtin_amdgcn_global_load_lds(                                     \
            (const __attribute__((address_space(1))) void*)(gB0 + ko_),       \
            (__attribute__((address_space(3))) void*)(bb_ + (w * 32) * 32),   \
            16, 0, 0);                                                        \
        __builtin_amdgcn_global_load_lds(                                     \
            (const __attribute__((address_space(1))) void*)(gB1 + ko_),       \
            (__attribute__((address_space(3))) void*)(bb_ + (w * 32 + 16) * 32),\
            16, 0, 0);                                                        \
    } while (0)

    #define A_WRITE(t, S) do {                                                \
        __bf16* d_ = lds + ((t) & 1) * ASLOT_E + arow * 32;                   \
        ushort8 w0, w1;                                                       \
        w0[0] = f2bf_rne(S.r0.x); w0[1] = f2bf_rne(S.r0.y);                   \
        w0[2] = f2bf_rne(S.r0.z); w0[3] = f2bf_rne(S.r0.w);                   \
        w0[4] = f2bf_rne(S.r1.x); w0[5] = f2bf_rne(S.r1.y);                   \
        w0[6] = f2bf_rne(S.r1.z); w0[7] = f2bf_rne(S.r1.w);                   \
        w1[0] = f2bf_rne(S.r2.x); w1[1] = f2bf_rne(S.r2.y);                   \
        w1[2] = f2bf_rne(S.r2.z); w1[3] = f2bf_rne(S.r2.w);                   \
        w1[4] = f2bf_rne(S.r3.x); w1[5] = f2bf_rne(S.r3.y);                   \
        w1[6] = f2bf_rne(S.r3.z); w1[7] = f2bf_rne(S.r3.w);                   \
        *(bf16x8*)(d_ + p0 * 8) = __builtin_bit_cast(bf16x8, w0);             \
        *(bf16x8*)(d_ + p1 * 8) = __builtin_bit_cast(bf16x8, w1);             \
    } while (0)

    #define COMPUTE(t) do {                                                   \
        const __bf16* pa_ = lds + ((t) & 1) * ASLOT_E + aoff0;                \
        const __bf16* pb_ = lds + BBASE_E + ((t) & 3) * ASLOT_E + boff0;      \
        bf16x8 bf_[4];                                                        \
        _Pragma("unroll")                                                     \
        for (int n = 0; n < 4; ++n) bf_[n] = *(const bf16x8*)(pb_ + n * 512); \
        __builtin_amdgcn_s_setprio(1);                                        \
        _Pragma("unroll")                                                     \
        for (int m = 0; m < 8; ++m) {                                         \
            bf16x8 af_ = *(const bf16x8*)(pa_ + m * 512);                     \
            _Pragma("unroll")                                                 \
            for (int n = 0; n < 4; ++n)                                       \
                acc[m][n] = __builtin_amdgcn_mfma_f32_16x16x32_bf16(          \
                    af_, bf_[n], acc[m][n], 0, 0, 0);                         \
        }                                                                     \
        __builtin_amdgcn_s_setprio(0);                                        \
    } while (0)

    // ITER(t): wait B(t) (counted); drain own ds ops; barrier; issue A(t+2)
    // into set SI; issue B(t+3) DMA; compute t; cvt+ds_write A(t+1) from
    // set SW (loaded a full iteration earlier — the compiler's in-order
    // reg-wait before the cvt drains only OLDER vm-ops, incl. B(t)).
    #define ITER(t, FS, SI, SW, DA, DB, DW) do {                              \
        asm volatile("s_waitcnt vmcnt(" FS ")" ::: "memory");                 \
        asm volatile("s_waitcnt lgkmcnt(0)" ::: "memory");                    \
        __builtin_amdgcn_s_barrier();                                         \
        FENCE;                                                                \
        if (DA) { A_ISSUE((t) + 2, SI); }                                     \
        FENCE;                                                                \
        if (DB) { B_ISSUE((t) + 3); }                                         \
        FENCE;                                                                \
        COMPUTE(t);                                                           \
        if (DW) { A_WRITE((t) + 1, SW); }                                     \
    } while (0)

    // prologue (ORDER MATTERS): A(0), B(0), A(1), B(1), B(2) — B(0) older
    // than A(1) so ITER(0)'s vmcnt(8) drains it; B(1) drained by ITER(1)'s.
    A_ISSUE(0, sA); FENCE;
    B_ISSUE(0); FENCE;
    A_ISSUE(1, sB); FENCE;
    B_ISSUE(1); FENCE; B_ISSUE(2); FENCE;
    A_WRITE(0, sA);      // compiler waits A(0) only (in-order, 10 newer live)

    // steady invariant at top of ITER(t): outstanding = [B(t+1):2,
    // A-set(t+1):4, B(t+2):2] = 8 and B(t) complete (t>=2: guaranteed by
    // the A_WRITE reg-wait at end of iter t-1; t=0,1: by vmcnt(8) drain).
    for (int t = 0; t <= 123; t += 2) {
        ITER(t,     "8", sA, sB, 1, 1, 1);   // even: load->sA, write<-sB
        ITER(t + 1, "8", sB, sA, 1, 1, 1);   // odd:  load->sB, write<-sA
    }
    ITER(124, "8", sA, sB, 1, 1, 1);         // issues B(127) (last)
    ITER(125, "8", sB, sA, 1, 0, 1);         // A(127)->sB; write A(126)<-sA
    ITER(126, "6", sA, sB, 0, 0, 1);         // write A(127)<-sB
    ITER(127, "0", sA, sA, 0, 0, 0);         // compute only

    // C/D layout (m89-verified): col = lane&15, row = (lane>>4)*4 + reg
    const int crow = khr * 4;
    #pragma unroll
    for (int m = 0; m < 8; ++m)
        #pragma unroll
        for (int n = 0; n < 4; ++n) {
            float* cp = C + (m0 + wr * 128 + m * 16 + crow) * (long)N
                          + n0 + wc * 64 + n * 16 + lr;
            #pragma unroll
            for (int j = 0; j < 4; ++j) cp[(long)j * N] = acc[m][n][j];
        }
    #undef A_ISSUE
    #undef B_ISSUE
    #undef A_WRITE
    #undef COMPUTE
    #undef ITER
}

// ---------------------------------------------------------------------------
extern "C" void kernel_launch(void* const* d_in, const int* in_sizes, int n_in,
                              void* d_out, int out_size, void* d_ws, size_t ws_size,
                              hipStream_t stream) {
    const float* x   = (const float*)d_in[0];   // [4,2048,4096] fp32
    const float* cb  = (const float*)d_in[1];   // [32,256,128] fp32
    const int*   asn = (const int*)d_in[2];     // [4096,32] int32
    float* out = (float*)d_out;                 // [4,2048,4096] fp32

    unsigned short* Wb = (unsigned short*)d_ws; // 33.5 MB

    gather_w_kernel<<<2048, 256, 0, stream>>>(cb, asn, Wb);
    // 512 blocks = 32 m-tiles x 16 n-tiles; 96 KiB dynamic LDS
    gemm_fused_kernel<<<512, 512, 98304, stream>>>(
        x, (const __bf16*)Wb, out);
}